// Round 9
// baseline (965.442 us; speedup 1.0000x reference)
//
#include <hip/hip_runtime.h>

#define DI __device__ __forceinline__

typedef unsigned int uint;
typedef unsigned short ushort;
typedef _Float16 half2t __attribute__((ext_vector_type(2)));
typedef _Float16 f16x8 __attribute__((ext_vector_type(8)));
typedef float f32x4 __attribute__((ext_vector_type(4)));

#define VOCAB 50257
#define NEMB 48
#define HID 128
#define G4 512
#define NCLS 2000
#define BATCH 512
#define SEQ 1024

DI float sigm(float x) {
  return __builtin_amdgcn_rcpf(1.0f + __builtin_amdgcn_exp2f(-1.4426950408889634f * x));
}
DI float tanhfast(float x) {
  return 1.0f - 2.0f * __builtin_amdgcn_rcpf(__builtin_amdgcn_exp2f(2.8853900817779268f * x) + 1.0f);
}

// Barrier draining ONLY LDS (lgkmcnt); global-load prefetches (vmcnt) stay
// in flight across it.
DI void barrier_lds_only() {
  asm volatile("s_waitcnt lgkmcnt(0)" ::: "memory");
  __builtin_amdgcn_s_barrier();
  asm volatile("" ::: "memory");
}

// ---------------------------------------------------------------------------
// Phase A: P'[v][u][g] = emb[v] . w_ih[g*128+u] + b_ih + b_hh   (f16 out)
// Gate-interleaved: flat v*512 + u*4 + g  (u = hcol, g = i,f,c,o).
// ---------------------------------------------------------------------------
#define VROWS 32
__global__ __launch_bounds__(512) void build_P(
    const float* __restrict__ emb, const float* __restrict__ w_ih,
    const float* __restrict__ b_ih, const float* __restrict__ b_hh,
    _Float16* __restrict__ P)
{
  __shared__ __align__(16) float eL[VROWS][NEMB];
  const int tid = threadIdx.x;            // gate col j = tid
  const int v0 = blockIdx.x * VROWS;
  int nrows = VOCAB - v0; if (nrows > VROWS) nrows = VROWS;

  for (int f = tid; f < nrows * NEMB; f += 512)
    eL[f / NEMB][f % NEMB] = emb[(size_t)v0 * NEMB + f];

  float w[NEMB];
  {
    const float* wr = w_ih + (size_t)tid * NEMB;
#pragma unroll
    for (int k = 0; k < NEMB; k++) w[k] = wr[k];
  }
  float bias = b_ih[tid] + b_hh[tid];
  const int pidx = ((tid & 127) << 2) + (tid >> 7);  // u*4 + g
  __syncthreads();

  for (int v = 0; v < nrows; v++) {
    const float4* e4 = (const float4*)&eL[v][0];
    float a = bias;
#pragma unroll
    for (int k = 0; k < NEMB / 4; k++) {
      float4 e = e4[k];
      a += w[4 * k] * e.x + w[4 * k + 1] * e.y + w[4 * k + 2] * e.z + w[4 * k + 3] * e.w;
    }
    P[(size_t)(v0 + v) * G4 + pidx] = (_Float16)a;
  }
}

// ---------------------------------------------------------------------------
// Phase B: MFMA LSTM scan, fused gates, M=1 row/block x 512 blocks ->
// TWO independent blocks per CU (16 waves/CU, 4/SIMD). While one block's
// waves stall at the barrier / A-read latency, the other block issues --
// the R8 lockstep-stall (~800 cyc/step) converts to overlap. Per block:
// 512 threads (8 waves); wave w owns all four gates of hcols w*16..w*16+15
// (Bf[g] = W_hh rows g*128+u). C layout (col=lane&15, row=4*lg+reg): batch
// row 0 lives in reg 0 of lg==0 lanes -> gates fully in-register there.
// Double-buffered hbuf[2] + ONE lgkm-only barrier per step. xg prefetched
// 2 steps deep, captured before overwrite.
// ---------------------------------------------------------------------------
__global__ __launch_bounds__(512, 4) void lstm_mfma5(
    const int* __restrict__ x, const float* __restrict__ w_hh,
    const _Float16* __restrict__ P, float* __restrict__ hout)
{
  __shared__ ushort tokL[SEQ];                            // 2 KB
  __shared__ __align__(16) _Float16 hbuf[2][16][HID];     // 8 KB, rows 1..15 stay 0

  const int tid  = threadIdx.x;
  const int lane = tid & 63;
  const int wave = tid >> 6;        // 0..7
  const int l15  = lane & 15;
  const int lg   = lane >> 4;       // 0..3
  const int u    = wave * 16 + l15; // hcol this lane owns (gates, lg==0 only)
  const int blk  = blockIdx.x;      // batch row

  // stage tokens as u16 (VOCAB < 65536)
  {
    const int* xp = x + (size_t)blk * SEQ;
#pragma unroll
    for (int i = 0; i < SEQ / 512; i++) tokL[tid + 512 * i] = (ushort)xp[tid + 512 * i];
  }
  // zero both hbuf parities (8192 B = 512 x 16 B)
  {
    uint4 z; z.x = z.y = z.z = z.w = 0u;
    ((uint4*)hbuf)[tid] = z;
  }

  // B fragments: Bf[g][ck] = W_hh[g*128 + u][ck*32 + lg*8 .. +7]  (f16)
  f16x8 Bf[4][4];
#pragma unroll
  for (int g = 0; g < 4; g++) {
    const float* wr = w_hh + (size_t)(g * 128 + u) * HID + lg * 8;
#pragma unroll
    for (int ck = 0; ck < 4; ck++) {
      const float4* p4 = (const float4*)(wr + ck * 32);
      float4 wa = p4[0], wb = p4[1];
      f16x8 f;
      f[0] = (_Float16)wa.x; f[1] = (_Float16)wa.y;
      f[2] = (_Float16)wa.z; f[3] = (_Float16)wa.w;
      f[4] = (_Float16)wb.x; f[5] = (_Float16)wb.y;
      f[6] = (_Float16)wb.z; f[7] = (_Float16)wb.w;
      Bf[g][ck] = f;
    }
  }

  // A-read offsets: row=l15, logical granule (ck*4+lg), physical = logical^row
  int aoff[4];
#pragma unroll
  for (int ck = 0; ck < 4; ck++)
    aoff[ck] = l15 * 256 + ((((ck * 4 + lg) ^ l15)) << 4);

  // h-write offset (row 0 => swizzle is identity)
  const int hwoff0 = u * 2;
  float cst0 = 0.0f;

  __syncthreads();  // tokens + zeroed hbuf visible

  // xg prefetch, 2 deep, on lg==0 lanes only
  uint2 xgA0 = {0, 0}, xgB0 = {0, 0};
  if (lg == 0) {
    xgA0 = *(const uint2*)(P + (size_t)tokL[0] * G4 + u * 4);
    xgB0 = *(const uint2*)(P + (size_t)tokL[1] * G4 + u * 4);
  }

  const f32x4 fz = {0.f, 0.f, 0.f, 0.f};
  const char* hB = (const char*)hbuf;
  char* hW = (char*)hbuf;

#define MF(Areg, ckk, a0, a1, a2, a3) do {                                     \
    a0 = __builtin_amdgcn_mfma_f32_16x16x32_f16(Areg, Bf[0][ckk], a0, 0, 0, 0);\
    a1 = __builtin_amdgcn_mfma_f32_16x16x32_f16(Areg, Bf[1][ckk], a1, 0, 0, 0);\
    a2 = __builtin_amdgcn_mfma_f32_16x16x32_f16(Areg, Bf[2][ckk], a2, 0, 0, 0);\
    a3 = __builtin_amdgcn_mfma_f32_16x16x32_f16(Areg, Bf[3][ckk], a3, 0, 0, 0);\
  } while (0)

#define STEP(t, par) do {                                                      \
    const char* hc = hB + (par) * 4096;                                        \
    f16x8 A0 = *(const f16x8*)(hc + aoff[0]);                                  \
    f16x8 A1 = *(const f16x8*)(hc + aoff[1]);                                  \
    f16x8 A2 = *(const f16x8*)(hc + aoff[2]);                                  \
    f16x8 A3 = *(const f16x8*)(hc + aoff[3]);                                  \
    f32x4 a0 = fz, a1 = fz, a2 = fz, a3 = fz;                                  \
    MF(A0, 0, a0, a1, a2, a3);                                                 \
    MF(A1, 1, a0, a1, a2, a3);                                                 \
    MF(A2, 2, a0, a1, a2, a3);                                                 \
    MF(A3, 3, a0, a1, a2, a3);                                                 \
    if (lg == 0) {                                                             \
      uint2 xc0 = (par) ? xgB0 : xgA0;  /* capture BEFORE overwrite */         \
      int tc = (t) + 2; if (tc > SEQ - 1) tc = SEQ - 1;                        \
      int tk0 = tokL[tc];                                                      \
      uint2 v0 = *(const uint2*)(P + (size_t)tk0 * G4 + u * 4);                \
      if (par) xgB0 = v0; else xgA0 = v0;                                      \
      char* hn = hW + ((par) ^ 1) * 4096;                                      \
      half2t x0 = __builtin_bit_cast(half2t, xc0.x);                           \
      half2t x1 = __builtin_bit_cast(half2t, xc0.y);                           \
      float gi = a0[0] + (float)x0.x;                                          \
      float gf = a1[0] + (float)x0.y;                                          \
      float gc = a2[0] + (float)x1.x;                                          \
      float go = a3[0] + (float)x1.y;                                          \
      float fi = sigm(gi), ff = sigm(gf), gt = tanhfast(gc), fo = sigm(go);    \
      cst0 = ff * cst0 + fi * gt;                                              \
      float hh = fo * tanhfast(cst0);                                          \
      *(_Float16*)(hn + hwoff0) = (_Float16)hh;                                \
      if ((t) == SEQ - 1)                                                      \
        hout[(size_t)blk * HID + u] = hh;                                      \
    }                                                                          \
    barrier_lds_only();                                                        \
  } while (0)

  for (int t = 0; t < SEQ; t += 2) { STEP(t, 0); STEP(t + 1, 1); }
#undef STEP
#undef MF
}

// ---------------------------------------------------------------------------
// Fallback scan (no workspace for P): one row per block, fma path.
// ---------------------------------------------------------------------------
typedef _Float16 h2 __attribute__((ext_vector_type(2)));
DI float fdot2f(h2 a, h2 b, float c) { return c + (float)a.x * (float)b.x + (float)a.y * (float)b.y; }

__global__ __launch_bounds__(512, 4) void lstm_scan_fb(
    const int* __restrict__ x, const float* __restrict__ emb,
    const float* __restrict__ w_ih, const float* __restrict__ w_hh,
    const float* __restrict__ b_ih, const float* __restrict__ b_hh,
    float* __restrict__ hout)
{
  __shared__ int tokL[SEQ];
  __shared__ __align__(16) _Float16 h16[HID];
  __shared__ float g2h[2][G4];
  __shared__ __align__(8) h2 e16[2][NEMB / 2];

  const int tid = threadIdx.x;
  const int b = blockIdx.x;
  const int col = tid & 255;
  const int kh = tid >> 8;
  const int koff = kh * (HID / 2);

  {
    const int* xp = x + (size_t)b * SEQ;
#pragma unroll
    for (int i = 0; i < SEQ / 512; i++) tokL[tid + 512 * i] = xp[tid + 512 * i];
  }

  h2 w0[HID / 4], w1[HID / 4];
  {
    const float4* wr0 = (const float4*)(w_hh + (size_t)col * HID + koff);
    const float4* wr1 = (const float4*)(w_hh + (size_t)(col + 256) * HID + koff);
#pragma unroll
    for (int k = 0; k < HID / 8; k++) {
      float4 a = wr0[k];
      h2 p; p.x = (_Float16)a.x; p.y = (_Float16)a.y; w0[2 * k] = p;
      p.x = (_Float16)a.z; p.y = (_Float16)a.w; w0[2 * k + 1] = p;
      float4 bv = wr1[k];
      p.x = (_Float16)bv.x; p.y = (_Float16)bv.y; w1[2 * k] = p;
      p.x = (_Float16)bv.z; p.y = (_Float16)bv.w; w1[2 * k + 1] = p;
    }
  }
  h2 wih0[NEMB / 2], wih1[NEMB / 2];
  float bias0 = 0.0f, bias1 = 0.0f;
  if (kh == 0) {
    const float* wr0 = w_ih + (size_t)col * NEMB;
    const float* wr1 = w_ih + (size_t)(col + 256) * NEMB;
#pragma unroll
    for (int k = 0; k < NEMB / 2; k++) {
      h2 p;
      p.x = (_Float16)wr0[2 * k]; p.y = (_Float16)wr0[2 * k + 1]; wih0[k] = p;
      p.x = (_Float16)wr1[2 * k]; p.y = (_Float16)wr1[2 * k + 1]; wih1[k] = p;
    }
    bias0 = b_ih[col] + b_hh[col];
    bias1 = b_ih[col + 256] + b_hh[col + 256];
  }
  if (tid < HID) h16[tid] = (_Float16)0.0f;
  __syncthreads();

  float c = 0.0f;
  float2 einfl = {0.0f, 0.0f};
  if (tid < NEMB / 2) {
    float2 e0 = ((const float2*)(emb + (size_t)tokL[0] * NEMB))[tid];
    einfl    = ((const float2*)(emb + (size_t)tokL[1] * NEMB))[tid];
    h2 p; p.x = (_Float16)e0.x; p.y = (_Float16)e0.y;
    e16[0][tid] = p;
  }
  __syncthreads();

#define STEPF(t, par) do {                                                     \
    float xg0, xg1;                                                            \
    if (tid < NEMB / 2) {                                                      \
      int tc = (t) + 2; if (tc > SEQ - 1) tc = SEQ - 1;                        \
      h2 p; p.x = (_Float16)einfl.x; p.y = (_Float16)einfl.y;                  \
      e16[((t) + 1) & 1][tid] = p;                                             \
      einfl = ((const float2*)(emb + (size_t)tokL[tc] * NEMB))[tid];           \
    }                                                                          \
    if (kh == 0) {                                                             \
      xg0 = bias0; xg1 = bias1;                                                \
      _Pragma("unroll")                                                        \
      for (int k = 0; k < NEMB / 2; k++) {                                     \
        xg0 = fdot2f(wih0[k], e16[(par)][k], xg0);                             \
        xg1 = fdot2f(wih1[k], e16[(par)][k], xg1);                             \
      }                                                                        \
    } else { xg0 = 0.0f; xg1 = 0.0f; }                                         \
    const uint4* hv = (const uint4*)h16 + (kh << 3);                           \
    float s0 = xg0, u0 = 0.0f, s1 = xg1, u1 = 0.0f;                            \
    _Pragma("unroll")                                                          \
    for (int kt = 0; kt < HID / 16; kt++) {                                    \
      uint4 hq = hv[kt];                                                       \
      h2 ha = __builtin_bit_cast(h2, hq.x);                                    \
      h2 hb = __builtin_bit_cast(h2, hq.y);                                    \
      h2 hc = __builtin_bit_cast(h2, hq.z);                                    \
      h2 hd = __builtin_bit_cast(h2, hq.w);                                    \
      s0 = fdot2f(w0[4 * kt + 0], ha, s0);                                     \
      u0 = fdot2f(w0[4 * kt + 1], hb, u0);                                     \
      s0 = fdot2f(w0[4 * kt + 2], hc, s0);                                     \
      u0 = fdot2f(w0[4 * kt + 3], hd, u0);                                     \
      s1 = fdot2f(w1[4 * kt + 0], ha, s1);                                     \
      u1 = fdot2f(w1[4 * kt + 1], hb, u1);                                     \
      s1 = fdot2f(w1[4 * kt + 2], hc, s1);                                     \
      u1 = fdot2f(w1[4 * kt + 3], hd, u1);                                     \
    }                                                                          \
    g2h[kh][col] = s0 + u0;                                                    \
    g2h[kh][col + 256] = s1 + u1;                                              \
    barrier_lds_only();                                                        \
    if (tid < HID) {                                                           \
      float gi = g2h[0][tid]           + g2h[1][tid];                          \
      float gf = g2h[0][HID + tid]     + g2h[1][HID + tid];                    \
      float gc = g2h[0][2 * HID + tid] + g2h[1][2 * HID + tid];                \
      float go = g2h[0][3 * HID + tid] + g2h[1][3 * HID + tid];                \
      float fi = sigm(gi), ff = sigm(gf), gt = tanhfast(gc), fo = sigm(go);    \
      c = ff * c + fi * gt;                                                    \
      float hh = fo * tanhfast(c);                                             \
      h16[tid] = (_Float16)hh;                                                 \
      if ((t) == SEQ - 1) hout[(size_t)b * HID + tid] = hh;                    \
    }                                                                          \
    barrier_lds_only();                                                        \
  } while (0)

  for (int t = 0; t < SEQ; t += 2) { STEPF(t, 0); STEPF(t + 1, 1); }
#undef STEPF
}

// ---------------------------------------------------------------------------
// Phase C: FC  out[512,2000] = h[512,128] @ w_fc^T + b_fc.
// ---------------------------------------------------------------------------
#define FCR 64
#define FCC 64
__global__ __launch_bounds__(256) void fc_kernel(
    const float* __restrict__ h, const float* __restrict__ w_fc,
    const float* __restrict__ b_fc, float* __restrict__ out)
{
  __shared__ float aT[HID][FCR];
  __shared__ float bT[HID][FCC];
  const int tid = threadIdx.x;
  const int r0 = blockIdx.y * FCR;
  const int c0 = blockIdx.x * FCC;

  for (int f = tid; f < FCR * (HID / 4); f += 256) {
    int row = f >> 5, q = f & 31;
    float4 v = ((const float4*)h)[(((size_t)(r0 + row)) << 5) + q];
    aT[4 * q + 0][row] = v.x; aT[4 * q + 1][row] = v.y;
    aT[4 * q + 2][row] = v.z; aT[4 * q + 3][row] = v.w;
    int wrow = c0 + row;
    float4 wv;
    if (wrow < NCLS) wv = ((const float4*)w_fc)[(((size_t)wrow) << 5) + q];
    else { wv.x = 0.f; wv.y = 0.f; wv.z = 0.f; wv.w = 0.f; }
    bT[4 * q + 0][row] = wv.x; bT[4 * q + 1][row] = wv.y;
    bT[4 * q + 2][row] = wv.z; bT[4 * q + 3][row] = wv.w;
  }
  __syncthreads();

  const int cr = tid & 15, rr = tid >> 4;
  float acc[4][4];
#pragma unroll
  for (int i = 0; i < 4; i++)
#pragma unroll
    for (int j = 0; j < 4; j++) acc[i][j] = 0.0f;

#pragma unroll 4
  for (int k = 0; k < HID; k++) {
    float4 av = *(const float4*)&aT[k][4 * rr];
    float4 bv = *(const float4*)&bT[k][4 * cr];
    float a[4] = {av.x, av.y, av.z, av.w};
    float bb[4] = {bv.x, bv.y, bv.z, bv.w};
#pragma unroll
    for (int i = 0; i < 4; i++)
#pragma unroll
      for (int j = 0; j < 4; j++) acc[i][j] += a[i] * bb[j];
  }

#pragma unroll
  for (int j = 0; j < 4; j++) {
    int cc = c0 + 4 * cr + j;
    if (cc < NCLS) {
      float bias = b_fc[cc];
#pragma unroll
      for (int i = 0; i < 4; i++)
        out[(size_t)(r0 + 4 * rr + i) * NCLS + cc] = acc[i][j] + bias;
    }
  }
}

extern "C" void kernel_launch(void* const* d_in, const int* in_sizes, int n_in,
                              void* d_out, int out_size, void* d_ws, size_t ws_size,
                              hipStream_t stream) {
  const int*   xx   = (const int*)d_in[0];
  const float* emb  = (const float*)d_in[1];
  const float* w_ih = (const float*)d_in[2];
  const float* w_hh = (const float*)d_in[3];
  const float* b_ih = (const float*)d_in[4];
  const float* b_hh = (const float*)d_in[5];
  const float* w_fc = (const float*)d_in[6];
  const float* b_fc = (const float*)d_in[7];
  float* out = (float*)d_out;

  const size_t pbytes = (size_t)VOCAB * G4 * sizeof(_Float16); // 51.5 MB
  const size_t palign = (pbytes + 255) & ~(size_t)255;
  const size_t hbytes = (size_t)BATCH * HID * sizeof(float);

  float* hout;
  if (ws_size >= palign + hbytes) {
    _Float16* P = (_Float16*)d_ws;
    hout = (float*)((char*)d_ws + palign);
    build_P<<<(VOCAB + VROWS - 1) / VROWS, 512, 0, stream>>>(emb, w_ih, b_ih, b_hh, P);
    lstm_mfma5<<<BATCH, 512, 0, stream>>>(xx, w_hh, P, hout);
  } else {
    hout = (float*)d_ws;
    lstm_scan_fb<<<BATCH, 512, 0, stream>>>(xx, emb, w_ih, w_hh, b_ih, b_hh, hout);
  }
  dim3 fcg((NCLS + FCC - 1) / FCC, BATCH / FCR);
  fc_kernel<<<fcg, 256, 0, stream>>>(hout, w_fc, b_fc, out);
}

// Round 10
// 826.585 us; speedup vs baseline: 1.1680x; 1.1680x over previous
//
#include <hip/hip_runtime.h>

#define DI __device__ __forceinline__

typedef unsigned int uint;
typedef unsigned short ushort;
typedef _Float16 half2t __attribute__((ext_vector_type(2)));
typedef _Float16 f16x8 __attribute__((ext_vector_type(8)));
typedef float f32x4 __attribute__((ext_vector_type(4)));

#define VOCAB 50257
#define NEMB 48
#define HID 128
#define G4 512
#define NCLS 2000
#define BATCH 512
#define SEQ 1024
#define MROWS 2
#define NBLK2 (BATCH / MROWS)   // 256 blocks -> 1 per CU

DI float sigm(float x) {
  return __builtin_amdgcn_rcpf(1.0f + __builtin_amdgcn_exp2f(-1.4426950408889634f * x));
}
DI float tanhfast(float x) {
  return 1.0f - 2.0f * __builtin_amdgcn_rcpf(__builtin_amdgcn_exp2f(2.8853900817779268f * x) + 1.0f);
}

// Barrier draining ONLY LDS (lgkmcnt); global-load prefetches (vmcnt) stay
// in flight across it.
DI void barrier_lds_only() {
  asm volatile("s_waitcnt lgkmcnt(0)" ::: "memory");
  __builtin_amdgcn_s_barrier();
  asm volatile("" ::: "memory");
}

// ---------------------------------------------------------------------------
// Phase A: P'[v][u][g] = emb[v] . w_ih[g*128+u] + b_ih + b_hh   (f16 out)
// Gate-interleaved: flat v*512 + u*4 + g  (u = hcol, g = i,f,c,o).
// ---------------------------------------------------------------------------
#define VROWS 32
__global__ __launch_bounds__(512) void build_P(
    const float* __restrict__ emb, const float* __restrict__ w_ih,
    const float* __restrict__ b_ih, const float* __restrict__ b_hh,
    _Float16* __restrict__ P)
{
  __shared__ __align__(16) float eL[VROWS][NEMB];
  const int tid = threadIdx.x;            // gate col j = tid
  const int v0 = blockIdx.x * VROWS;
  int nrows = VOCAB - v0; if (nrows > VROWS) nrows = VROWS;

  for (int f = tid; f < nrows * NEMB; f += 512)
    eL[f / NEMB][f % NEMB] = emb[(size_t)v0 * NEMB + f];

  float w[NEMB];
  {
    const float* wr = w_ih + (size_t)tid * NEMB;
#pragma unroll
    for (int k = 0; k < NEMB; k++) w[k] = wr[k];
  }
  float bias = b_ih[tid] + b_hh[tid];
  const int pidx = ((tid & 127) << 2) + (tid >> 7);  // u*4 + g
  __syncthreads();

  for (int v = 0; v < nrows; v++) {
    const float4* e4 = (const float4*)&eL[v][0];
    float a = bias;
#pragma unroll
    for (int k = 0; k < NEMB / 4; k++) {
      float4 e = e4[k];
      a += w[4 * k] * e.x + w[4 * k + 1] * e.y + w[4 * k + 2] * e.z + w[4 * k + 3] * e.w;
    }
    P[(size_t)(v0 + v) * G4 + pidx] = (_Float16)a;
  }
}

// ---------------------------------------------------------------------------
// Phase B: MFMA LSTM scan, fused gates, ROW-SPLIT gate phase. M=2 rows/block
// x 256 blocks, 512 threads (8 waves). Wave w owns all four gates of hcols
// w*16..w*16+15 (Bf[g] = W_hh rows g*128+u). C layout (col=lane&15,
// row=4*lg+reg): lanes lg==0 hold row 0 in reg 0, row 1 in reg 1.
// After MFMA, lg==0 writes its reg-1 values (row 1, 4 gates) to per-wave
// LDS scratch xch[wave][gate][l15]; lg==1 reads them back (same-wave DS
// ordering, no barrier). lg==0 gates row 0, lg==1 gates row 1 -> trans
// issue per wave halves (20 -> 10). Double-buffered hbuf[2] + ONE lgkm-only
// barrier per step (R4/R8-verified skeleton). xg prefetched 2 steps deep,
// captured before overwrite (R5 lesson); each lane handles its own row lg.
// ---------------------------------------------------------------------------
__global__ __launch_bounds__(512, 2) void lstm_mfma6(
    const int* __restrict__ x, const float* __restrict__ w_hh,
    const _Float16* __restrict__ P, float* __restrict__ hout)
{
  __shared__ ushort tokL[MROWS][SEQ];                     // 4 KB
  __shared__ __align__(16) _Float16 hbuf[2][16][HID];     // 8 KB, rows 2..15 stay 0
  __shared__ float xch[8][4][16];                         // 2 KB row-1 exchange

  const int tid  = threadIdx.x;
  const int lane = tid & 63;
  const int wave = tid >> 6;        // 0..7
  const int l15  = lane & 15;
  const int lg   = lane >> 4;       // 0..3
  const int u    = wave * 16 + l15; // hcol this lane owns (gates on lg<2)
  const int blk  = blockIdx.x;

  // stage tokens as u16 (VOCAB < 65536)
  {
    const int* xp = x + (size_t)blk * MROWS * SEQ;
    for (int i = tid; i < MROWS * SEQ; i += 512) ((ushort*)tokL)[i] = (ushort)xp[i];
  }
  // zero both hbuf parities (8192 B = 512 x 16 B)
  {
    uint4 z; z.x = z.y = z.z = z.w = 0u;
    ((uint4*)hbuf)[tid] = z;
  }

  // B fragments: Bf[g][ck] = W_hh[g*128 + u][ck*32 + lg*8 .. +7]  (f16)
  f16x8 Bf[4][4];
#pragma unroll
  for (int g = 0; g < 4; g++) {
    const float* wr = w_hh + (size_t)(g * 128 + u) * HID + lg * 8;
#pragma unroll
    for (int ck = 0; ck < 4; ck++) {
      const float4* p4 = (const float4*)(wr + ck * 32);
      float4 wa = p4[0], wb = p4[1];
      f16x8 f;
      f[0] = (_Float16)wa.x; f[1] = (_Float16)wa.y;
      f[2] = (_Float16)wa.z; f[3] = (_Float16)wa.w;
      f[4] = (_Float16)wb.x; f[5] = (_Float16)wb.y;
      f[6] = (_Float16)wb.z; f[7] = (_Float16)wb.w;
      Bf[g][ck] = f;
    }
  }

  // A-read offsets: row=l15, logical granule (ck*4+lg), physical = logical^row
  int aoff[4];
#pragma unroll
  for (int ck = 0; ck < 4; ck++)
    aoff[ck] = l15 * 256 + ((((ck * 4 + lg) ^ l15)) << 4);

  // h-write offset for gate lanes (lg<2): row=lg, col=u, phys granule (u>>3)^lg
  const int hwoff = lg * 256 + (((u >> 3) ^ (lg & 1)) << 4) + (u & 7) * 2;
  float cst = 0.0f;

  __syncthreads();  // tokens + zeroed hbuf visible

  // xg prefetch, 2 deep; lane handles its own row lg (lg<2 only)
  uint2 xgA = {0, 0}, xgB = {0, 0};
  if (lg < 2) {
    xgA = *(const uint2*)(P + (size_t)tokL[lg][0] * G4 + u * 4);
    xgB = *(const uint2*)(P + (size_t)tokL[lg][1] * G4 + u * 4);
  }

  const f32x4 fz = {0.f, 0.f, 0.f, 0.f};
  const char* hB = (const char*)hbuf;
  char* hW = (char*)hbuf;

#define MF(Areg, ckk, a0, a1, a2, a3) do {                                     \
    a0 = __builtin_amdgcn_mfma_f32_16x16x32_f16(Areg, Bf[0][ckk], a0, 0, 0, 0);\
    a1 = __builtin_amdgcn_mfma_f32_16x16x32_f16(Areg, Bf[1][ckk], a1, 0, 0, 0);\
    a2 = __builtin_amdgcn_mfma_f32_16x16x32_f16(Areg, Bf[2][ckk], a2, 0, 0, 0);\
    a3 = __builtin_amdgcn_mfma_f32_16x16x32_f16(Areg, Bf[3][ckk], a3, 0, 0, 0);\
  } while (0)

#define STEP(t, par) do {                                                      \
    const char* hc = hB + (par) * 4096;                                        \
    f16x8 A0 = *(const f16x8*)(hc + aoff[0]);                                  \
    f16x8 A1 = *(const f16x8*)(hc + aoff[1]);                                  \
    f16x8 A2 = *(const f16x8*)(hc + aoff[2]);                                  \
    f16x8 A3 = *(const f16x8*)(hc + aoff[3]);                                  \
    f32x4 a0 = fz, a1 = fz, a2 = fz, a3 = fz;                                  \
    MF(A0, 0, a0, a1, a2, a3);                                                 \
    MF(A1, 1, a0, a1, a2, a3);                                                 \
    MF(A2, 2, a0, a1, a2, a3);                                                 \
    MF(A3, 3, a0, a1, a2, a3);                                                 \
    /* row-1 values (reg 1 on lg==0) -> LDS exchange, same-wave ordering */    \
    if (lg == 0) {                                                             \
      xch[wave][0][l15] = a0[1];                                               \
      xch[wave][1][l15] = a1[1];                                               \
      xch[wave][2][l15] = a2[1];                                               \
      xch[wave][3][l15] = a3[1];                                               \
    }                                                                          \
    if (lg < 2) {                                                              \
      uint2 xcur = (par) ? xgB : xgA;   /* capture BEFORE overwrite */         \
      int tc = (t) + 2; if (tc > SEQ - 1) tc = SEQ - 1;                        \
      int tk = tokL[lg][tc];                                                   \
      uint2 v = *(const uint2*)(P + (size_t)tk * G4 + u * 4);                  \
      if (par) xgB = v; else xgA = v;                                          \
      float v0, v1, v2, v3;                                                    \
      if (lg == 0) { v0 = a0[0]; v1 = a1[0]; v2 = a2[0]; v3 = a3[0]; }         \
      else {                                                                   \
        v0 = xch[wave][0][l15]; v1 = xch[wave][1][l15];                        \
        v2 = xch[wave][2][l15]; v3 = xch[wave][3][l15];                        \
      }                                                                        \
      half2t x0 = __builtin_bit_cast(half2t, xcur.x);                          \
      half2t x1 = __builtin_bit_cast(half2t, xcur.y);                          \
      float gi = v0 + (float)x0.x;                                             \
      float gf = v1 + (float)x0.y;                                             \
      float gc = v2 + (float)x1.x;                                             \
      float go = v3 + (float)x1.y;                                             \
      float fi = sigm(gi), ff = sigm(gf), gt = tanhfast(gc), fo = sigm(go);    \
      cst = ff * cst + fi * gt;                                                \
      float hh = fo * tanhfast(cst);                                           \
      *(_Float16*)(hW + ((par) ^ 1) * 4096 + hwoff) = (_Float16)hh;            \
      if ((t) == SEQ - 1)                                                      \
        hout[((size_t)blk * MROWS + lg) * HID + u] = hh;                       \
    }                                                                          \
    barrier_lds_only();                                                        \
  } while (0)

  for (int t = 0; t < SEQ; t += 2) { STEP(t, 0); STEP(t + 1, 1); }
#undef STEP
#undef MF
}

// ---------------------------------------------------------------------------
// Fallback scan (no workspace for P): one row per block, fma path.
// ---------------------------------------------------------------------------
typedef _Float16 h2 __attribute__((ext_vector_type(2)));
DI float fdot2f(h2 a, h2 b, float c) { return c + (float)a.x * (float)b.x + (float)a.y * (float)b.y; }

__global__ __launch_bounds__(512, 4) void lstm_scan_fb(
    const int* __restrict__ x, const float* __restrict__ emb,
    const float* __restrict__ w_ih, const float* __restrict__ w_hh,
    const float* __restrict__ b_ih, const float* __restrict__ b_hh,
    float* __restrict__ hout)
{
  __shared__ int tokL[SEQ];
  __shared__ __align__(16) _Float16 h16[HID];
  __shared__ float g2h[2][G4];
  __shared__ __align__(8) h2 e16[2][NEMB / 2];

  const int tid = threadIdx.x;
  const int b = blockIdx.x;
  const int col = tid & 255;
  const int kh = tid >> 8;
  const int koff = kh * (HID / 2);

  {
    const int* xp = x + (size_t)b * SEQ;
#pragma unroll
    for (int i = 0; i < SEQ / 512; i++) tokL[tid + 512 * i] = xp[tid + 512 * i];
  }

  h2 w0[HID / 4], w1[HID / 4];
  {
    const float4* wr0 = (const float4*)(w_hh + (size_t)col * HID + koff);
    const float4* wr1 = (const float4*)(w_hh + (size_t)(col + 256) * HID + koff);
#pragma unroll
    for (int k = 0; k < HID / 8; k++) {
      float4 a = wr0[k];
      h2 p; p.x = (_Float16)a.x; p.y = (_Float16)a.y; w0[2 * k] = p;
      p.x = (_Float16)a.z; p.y = (_Float16)a.w; w0[2 * k + 1] = p;
      float4 bv = wr1[k];
      p.x = (_Float16)bv.x; p.y = (_Float16)bv.y; w1[2 * k] = p;
      p.x = (_Float16)bv.z; p.y = (_Float16)bv.w; w1[2 * k + 1] = p;
    }
  }
  h2 wih0[NEMB / 2], wih1[NEMB / 2];
  float bias0 = 0.0f, bias1 = 0.0f;
  if (kh == 0) {
    const float* wr0 = w_ih + (size_t)col * NEMB;
    const float* wr1 = w_ih + (size_t)(col + 256) * NEMB;
#pragma unroll
    for (int k = 0; k < NEMB / 2; k++) {
      h2 p;
      p.x = (_Float16)wr0[2 * k]; p.y = (_Float16)wr0[2 * k + 1]; wih0[k] = p;
      p.x = (_Float16)wr1[2 * k]; p.y = (_Float16)wr1[2 * k + 1]; wih1[k] = p;
    }
    bias0 = b_ih[col] + b_hh[col];
    bias1 = b_ih[col + 256] + b_hh[col + 256];
  }
  if (tid < HID) h16[tid] = (_Float16)0.0f;
  __syncthreads();

  float c = 0.0f;
  float2 einfl = {0.0f, 0.0f};
  if (tid < NEMB / 2) {
    float2 e0 = ((const float2*)(emb + (size_t)tokL[0] * NEMB))[tid];
    einfl    = ((const float2*)(emb + (size_t)tokL[1] * NEMB))[tid];
    h2 p; p.x = (_Float16)e0.x; p.y = (_Float16)e0.y;
    e16[0][tid] = p;
  }
  __syncthreads();

#define STEPF(t, par) do {                                                     \
    float xg0, xg1;                                                            \
    if (tid < NEMB / 2) {                                                      \
      int tc = (t) + 2; if (tc > SEQ - 1) tc = SEQ - 1;                        \
      h2 p; p.x = (_Float16)einfl.x; p.y = (_Float16)einfl.y;                  \
      e16[((t) + 1) & 1][tid] = p;                                             \
      einfl = ((const float2*)(emb + (size_t)tokL[tc] * NEMB))[tid];           \
    }                                                                          \
    if (kh == 0) {                                                             \
      xg0 = bias0; xg1 = bias1;                                                \
      _Pragma("unroll")                                                        \
      for (int k = 0; k < NEMB / 2; k++) {                                     \
        xg0 = fdot2f(wih0[k], e16[(par)][k], xg0);                             \
        xg1 = fdot2f(wih1[k], e16[(par)][k], xg1);                             \
      }                                                                        \
    } else { xg0 = 0.0f; xg1 = 0.0f; }                                         \
    const uint4* hv = (const uint4*)h16 + (kh << 3);                           \
    float s0 = xg0, u0 = 0.0f, s1 = xg1, u1 = 0.0f;                            \
    _Pragma("unroll")                                                          \
    for (int kt = 0; kt < HID / 16; kt++) {                                    \
      uint4 hq = hv[kt];                                                       \
      h2 ha = __builtin_bit_cast(h2, hq.x);                                    \
      h2 hb = __builtin_bit_cast(h2, hq.y);                                    \
      h2 hc = __builtin_bit_cast(h2, hq.z);                                    \
      h2 hd = __builtin_bit_cast(h2, hq.w);                                    \
      s0 = fdot2f(w0[4 * kt + 0], ha, s0);                                     \
      u0 = fdot2f(w0[4 * kt + 1], hb, u0);                                     \
      s0 = fdot2f(w0[4 * kt + 2], hc, s0);                                     \
      u0 = fdot2f(w0[4 * kt + 3], hd, u0);                                     \
      s1 = fdot2f(w1[4 * kt + 0], ha, s1);                                     \
      u1 = fdot2f(w1[4 * kt + 1], hb, u1);                                     \
      s1 = fdot2f(w1[4 * kt + 2], hc, s1);                                     \
      u1 = fdot2f(w1[4 * kt + 3], hd, u1);                                     \
    }                                                                          \
    g2h[kh][col] = s0 + u0;                                                    \
    g2h[kh][col + 256] = s1 + u1;                                              \
    barrier_lds_only();                                                        \
    if (tid < HID) {                                                           \
      float gi = g2h[0][tid]           + g2h[1][tid];                          \
      float gf = g2h[0][HID + tid]     + g2h[1][HID + tid];                    \
      float gc = g2h[0][2 * HID + tid] + g2h[1][2 * HID + tid];                \
      float go = g2h[0][3 * HID + tid] + g2h[1][3 * HID + tid];                \
      float fi = sigm(gi), ff = sigm(gf), gt = tanhfast(gc), fo = sigm(go);    \
      c = ff * c + fi * gt;                                                    \
      float hh = fo * tanhfast(c);                                             \
      h16[tid] = (_Float16)hh;                                                 \
      if ((t) == SEQ - 1) hout[(size_t)b * HID + tid] = hh;                    \
    }                                                                          \
    barrier_lds_only();                                                        \
  } while (0)

  for (int t = 0; t < SEQ; t += 2) { STEPF(t, 0); STEPF(t + 1, 1); }
#undef STEPF
}

// ---------------------------------------------------------------------------
// Phase C: FC  out[512,2000] = h[512,128] @ w_fc^T + b_fc.
// ---------------------------------------------------------------------------
#define FCR 64
#define FCC 64
__global__ __launch_bounds__(256) void fc_kernel(
    const float* __restrict__ h, const float* __restrict__ w_fc,
    const float* __restrict__ b_fc, float* __restrict__ out)
{
  __shared__ float aT[HID][FCR];
  __shared__ float bT[HID][FCC];
  const int tid = threadIdx.x;
  const int r0 = blockIdx.y * FCR;
  const int c0 = blockIdx.x * FCC;

  for (int f = tid; f < FCR * (HID / 4); f += 256) {
    int row = f >> 5, q = f & 31;
    float4 v = ((const float4*)h)[(((size_t)(r0 + row)) << 5) + q];
    aT[4 * q + 0][row] = v.x; aT[4 * q + 1][row] = v.y;
    aT[4 * q + 2][row] = v.z; aT[4 * q + 3][row] = v.w;
    int wrow = c0 + row;
    float4 wv;
    if (wrow < NCLS) wv = ((const float4*)w_fc)[(((size_t)wrow) << 5) + q];
    else { wv.x = 0.f; wv.y = 0.f; wv.z = 0.f; wv.w = 0.f; }
    bT[4 * q + 0][row] = wv.x; bT[4 * q + 1][row] = wv.y;
    bT[4 * q + 2][row] = wv.z; bT[4 * q + 3][row] = wv.w;
  }
  __syncthreads();

  const int cr = tid & 15, rr = tid >> 4;
  float acc[4][4];
#pragma unroll
  for (int i = 0; i < 4; i++)
#pragma unroll
    for (int j = 0; j < 4; j++) acc[i][j] = 0.0f;

#pragma unroll 4
  for (int k = 0; k < HID; k++) {
    float4 av = *(const float4*)&aT[k][4 * rr];
    float4 bv = *(const float4*)&bT[k][4 * cr];
    float a[4] = {av.x, av.y, av.z, av.w};
    float bb[4] = {bv.x, bv.y, bv.z, bv.w};
#pragma unroll
    for (int i = 0; i < 4; i++)
#pragma unroll
      for (int j = 0; j < 4; j++) acc[i][j] += a[i] * bb[j];
  }

#pragma unroll
  for (int j = 0; j < 4; j++) {
    int cc = c0 + 4 * cr + j;
    if (cc < NCLS) {
      float bias = b_fc[cc];
#pragma unroll
      for (int i = 0; i < 4; i++)
        out[(size_t)(r0 + 4 * rr + i) * NCLS + cc] = acc[i][j] + bias;
    }
  }
}

extern "C" void kernel_launch(void* const* d_in, const int* in_sizes, int n_in,
                              void* d_out, int out_size, void* d_ws, size_t ws_size,
                              hipStream_t stream) {
  const int*   xx   = (const int*)d_in[0];
  const float* emb  = (const float*)d_in[1];
  const float* w_ih = (const float*)d_in[2];
  const float* w_hh = (const float*)d_in[3];
  const float* b_ih = (const float*)d_in[4];
  const float* b_hh = (const float*)d_in[5];
  const float* w_fc = (const float*)d_in[6];
  const float* b_fc = (const float*)d_in[7];
  float* out = (float*)d_out;

  const size_t pbytes = (size_t)VOCAB * G4 * sizeof(_Float16); // 51.5 MB
  const size_t palign = (pbytes + 255) & ~(size_t)255;
  const size_t hbytes = (size_t)BATCH * HID * sizeof(float);

  float* hout;
  if (ws_size >= palign + hbytes) {
    _Float16* P = (_Float16*)d_ws;
    hout = (float*)((char*)d_ws + palign);
    build_P<<<(VOCAB + VROWS - 1) / VROWS, 512, 0, stream>>>(emb, w_ih, b_ih, b_hh, P);
    lstm_mfma6<<<NBLK2, 512, 0, stream>>>(xx, w_hh, P, hout);
  } else {
    hout = (float*)d_ws;
    lstm_scan_fb<<<BATCH, 512, 0, stream>>>(xx, emb, w_ih, w_hh, b_ih, b_hh, hout);
  }
  dim3 fcg((NCLS + FCC - 1) / FCC, BATCH / FCR);
  fc_kernel<<<fcg, 256, 0, stream>>>(hout, w_fc, b_fc, out);
}